// Round 15
// baseline (2183.321 us; speedup 1.0000x reference)
//
#include <hip/hip_runtime.h>
#include <math.h>
#include <limits.h>

#define H 128
#define V 32000
#define CD 256
#define T_STEPS 21
#define NS 5
#define SOS 1
#define EOS 2
#define B 1024          // unique rows; reference B=5120 is 5 identical copies of each
#define BFULL 5120
#define NCHUNK 250      // V / 128

typedef _Float16 f16;
typedef f16   half8   __attribute__((ext_vector_type(8)));
typedef float floatx4 __attribute__((ext_vector_type(4)));
typedef unsigned short ushort8v __attribute__((ext_vector_type(8)));

#define AS1 __attribute__((address_space(1)))
#define AS3 __attribute__((address_space(3)))

__device__ __forceinline__ float bf2f(unsigned short u) {
    return __uint_as_float(((unsigned)u) << 16);
}

// np-faithful f32 sigmoid/tanh: f64 interior, single f32 round per np op.
__device__ __forceinline__ float sig32(float x) {
    float t = (float)exp(-(double)x);
    float r = __fadd_rn(1.0f, t);
    return __fdiv_rn(1.0f, r);
}
__device__ __forceinline__ float tanh32(float x) { return (float)tanh((double)x); }

// exact f64-recipe dot of p-row (f32, global) with W2 row v, k ascending.
// Vectorized loads; f64 add order identical to the scalar loop -> bit-identical.
__device__ __forceinline__ double w2dot(const float* __restrict__ pr,
                                        const void* __restrict__ W2_raw,
                                        int v, bool isf) {
    double acc = 0.0;
    if (isf) {
        const float* wv = (const float*)W2_raw + (long)v * H;
        #pragma unroll 8
        for (int k4 = 0; k4 < H / 4; ++k4) {
            float4 wq = *(const float4*)(wv + k4 * 4);
            float4 pq = *(const float4*)(pr + k4 * 4);
            acc += (double)pq.x * (double)wq.x;
            acc += (double)pq.y * (double)wq.y;
            acc += (double)pq.z * (double)wq.z;
            acc += (double)pq.w * (double)wq.w;
        }
    } else {
        const unsigned short* wv = (const unsigned short*)W2_raw + (long)v * H;
        #pragma unroll 8
        for (int k4 = 0; k4 < H / 4; ++k4) {
            ushort4 u = *(const ushort4*)(wv + k4 * 4);
            float4 pq = *(const float4*)(pr + k4 * 4);
            acc += (double)pq.x * (double)bf2f(u.x);
            acc += (double)pq.y * (double)bf2f(u.y);
            acc += (double)pq.z * (double)bf2f(u.z);
            acc += (double)pq.w * (double)bf2f(u.w);
        }
    }
    return acc;
}

// mask bit index for col c (0..127) in the byte-packed 128-bit record:
// byte (c&15) holds bits n for cols n*16+(c&15); bit index = (c&15)*8 + (c>>4).
__device__ __forceinline__ bool mask_test(unsigned long long m0, unsigned long long m1, int c) {
    int bidx = ((c & 15) << 3) + (c >> 4);
    unsigned long long word = (bidx < 64) ? m0 : m1;
    return (word >> (bidx & 63)) & 1ull;
}

// ---------------------------------------------------------------- input dtype sniffer
__global__ void k_detect(const unsigned short* __restrict__ e, int* __restrict__ flag) {
    int i = threadIdx.x;
    unsigned short u = e[2 * i];
    int ex = (u >> 7) & 0xFF;
    bool wild = ((u & 0x7FFF) != 0) && (ex < 0x60 || ex > 0x8F);
    unsigned long long m = __ballot(wild);
    if (i == 0) *flag = (m != 0ull) ? 1 : 0;   // 1 = f32 inputs, 0 = bf16
}

// ---------------------------------------------------------------- transcode ALL f32-bound inputs in one dispatch
struct TCArgs {
    const void* src[12];
    float*      dst[12];
    int         n[12];
};
__global__ __launch_bounds__(256) void k_transcode_all(TCArgs tc, const int* __restrict__ flag) {
    int which = blockIdx.y;
    float* d = tc.dst[which];
    if (d == nullptr) return;
    int i = blockIdx.x * 256 + threadIdx.x;
    if (i >= tc.n[which]) return;
    if (*flag) d[i] = ((const float*)tc.src[which])[i];
    else       d[i] = bf2f(((const unsigned short*)tc.src[which])[i]);
}

// ---------------------------------------------------------------- transpose Wih/Whh/W1 to k-pair-major [kp][col][2]
__global__ __launch_bounds__(256) void k_wtr(
    const float* __restrict__ Wih, const float* __restrict__ Whh,
    const float* __restrict__ W1, float* __restrict__ wihT,
    float* __restrict__ whhT, float* __restrict__ w1T) {
    int e = blockIdx.x * 256 + threadIdx.x;
    if (e < 512 * 128) {
        int col = e >> 7, k = e & 127;
        wihT[(k >> 1) * 1024 + col * 2 + (k & 1)] = Wih[e];
    } else if (e < 2 * 512 * 128) {
        int i = e - 512 * 128;
        int col = i >> 7, k = i & 127;
        whhT[(k >> 1) * 1024 + col * 2 + (k & 1)] = Whh[i];
    } else if (e < 2 * 512 * 128 + 128 * 128) {
        int i = e - 2 * 512 * 128;
        int col = i >> 7, k = i & 127;
        w1T[(k >> 1) * 256 + col * 2 + (k & 1)] = W1[i];
    }
}

// ---------------------------------------------------------------- W2: coalesced norm + scaled f16 hi/lo split (once per launch)
// Fragment-major wh/wl: f16 index = cb*16384 + kkg*1024 + row_local*8 + j.
__global__ __launch_bounds__(256) void k_wsplit(
    const void* __restrict__ W2_raw, unsigned short* __restrict__ wh,
    unsigned short* __restrict__ wl, float* __restrict__ wn,
    const int* __restrict__ flag) {
    int t = blockIdx.x * 256 + threadIdx.x;       // t in [0, V*H/8)
    const bool isf = (*flag != 0);
    int vrow = t >> 4;                            // vocab row
    int kkg  = t & 15;                            // which 8-wide k group
    float v[8];
    if (isf) {
        float4 f0 = ((const float4*)W2_raw)[2 * t];
        float4 f1 = ((const float4*)W2_raw)[2 * t + 1];
        v[0] = f0.x; v[1] = f0.y; v[2] = f0.z; v[3] = f0.w;
        v[4] = f1.x; v[5] = f1.y; v[6] = f1.z; v[7] = f1.w;
    } else {
        ushort8v u = ((const ushort8v*)W2_raw)[t];
        #pragma unroll
        for (int i = 0; i < 8; ++i) v[i] = bf2f(u[i]);
    }
    float s = 0.f;
    half8 hv, lv;
    #pragma unroll
    for (int i = 0; i < 8; ++i) {
        s += v[i] * v[i];
        float ws = v[i] * 256.0f;
        f16 hh = (f16)ws;
        hv[i] = hh;
        lv[i] = (f16)(ws - (float)hh);
    }
    int cb = vrow >> 7, rloc = vrow & 127;
    long dst = (long)cb * 16384 + kkg * 1024 + rloc * 8;
    *(half8*)((f16*)wh + dst) = hv;
    *(half8*)((f16*)wl + dst) = lv;
    // row norm: 16 consecutive threads share a row
    #pragma unroll
    for (int off = 1; off < 16; off <<= 1) s += __shfl_xor(s, off, 64);
    if (kkg == 0) wn[vrow] = sqrtf(s);
}

// ---------------------------------------------------------------- prep: wmax (block 4) + it/unf init (blocks 0-3)
__global__ __launch_bounds__(256) void k_prep(
    const float* __restrict__ wn, float* __restrict__ wmax,
    int* __restrict__ it, int* __restrict__ unf) {
    int tid = threadIdx.x;
    if (blockIdx.x < 4) {
        int i = blockIdx.x * 256 + tid;
        it[i] = SOS; unf[i] = 1;
        return;
    }
    __shared__ float red[4];
    float m = 0.f;
    for (int i = tid; i < V; i += 256) m = fmaxf(m, wn[i]);
    #pragma unroll
    for (int off = 1; off < 64; off <<= 1) m = fmaxf(m, __shfl_xor(m, off, 64));
    if ((tid & 63) == 0) red[tid >> 6] = m;
    __syncthreads();
    if (tid == 0) *wmax = fmaxf(fmaxf(red[0], red[1]), fmaxf(red[2], red[3]));
}

// ---------------------------------------------------------------- hc = fl32(x @ W_fc.T) + b_fc
__global__ __launch_bounds__(256) void k_init_hc(
    const float* __restrict__ xf, const float* __restrict__ Wfc,
    const float* __restrict__ bfc, float* __restrict__ h, float* __restrict__ c) {
    __shared__ float xl[CD];
    int r = blockIdx.x;
    int j = threadIdx.x;
    xl[j] = xf[(long)r * CD + j];
    __syncthreads();
    const float4* w4 = (const float4*)(Wfc + (long)j * CD);
    double acc = 0.0;
    for (int k4 = 0; k4 < CD / 4; ++k4) {
        float4 w = w4[k4];
        int k = k4 * 4;
        acc += (double)xl[k]     * (double)w.x;
        acc += (double)xl[k + 1] * (double)w.y;
        acc += (double)xl[k + 2] * (double)w.z;
        acc += (double)xl[k + 3] * (double)w.w;
    }
    float hc = __fadd_rn((float)acc, bfc[j]);
    if (j < H) h[(long)r * H + j] = hc;
    else       c[(long)r * H + (j - H)] = hc;
}

// ---------------------------------------------------------------- fused F(t-1) + G(t), 512 blocks x 256 threads, 2 rows/block
// (4 blocks/CU = 16 waves/CU; F runs on waves 0-1 of 4 = 50% duty, and 4
// independent blocks per CU overlap F-idle with G-compute across blocks).
// Phase F: mask-selected exact rescue, block-staged cm/cs, register-cached
// pass B (spill fallback). Phase G: transposed-weight gates (thread owns
// columns {tid, tid+256} x 2 rows — per-column k-ascending f64 chains
// unchanged), cell, proj. All emitted f32 values bit-identical.
__global__ __launch_bounds__(256, 4) void k_gf(
    const float* __restrict__ cmT, const float* __restrict__ csT,
    const unsigned long long* __restrict__ maskbuf,
    const void* __restrict__ W2_raw,
    const float* __restrict__ b2, const float* __restrict__ wmax,
    const void* __restrict__ embed_raw, float* __restrict__ h, float* __restrict__ c,
    const float* __restrict__ wihT, const float* __restrict__ whhT,
    const float* __restrict__ bih, const float* __restrict__ bhh,
    const float* __restrict__ w1T, const float* __restrict__ b1,
    float* __restrict__ p32, unsigned short* __restrict__ ph,
    unsigned short* __restrict__ pl, float* __restrict__ pnorm,
    int* __restrict__ it, int* __restrict__ unf, float* __restrict__ out,
    int t, const int* __restrict__ flag) {
    __shared__ float As[2][256];    // concat(e_tok, h) per row
    __shared__ float gsh[2][512];   // gates
    __shared__ float hl[2][132];
    __shared__ float2 cmsh[256];    // staged cm for rows rb, rb+1
    __shared__ float2 cssh[256];
    __shared__ float redp[4];
    const bool isf = (*flag != 0);
    int tid = threadIdx.x;
    int rb = blockIdx.x * 2;
    int lane = tid & 63, wid = tid >> 6;

    // ---- stage cm/cs for this block's 2 rows (parallel scattered loads)
    if (t > 0 && tid < NCHUNK) {
        cmsh[tid] = *(const float2*)(cmT + (long)tid * B + rb);
        cssh[tid] = *(const float2*)(csT + (long)tid * B + rb);
    }
    __syncthreads();

    // ================= F: finalize step t-1 for row rb+wid (waves 0-1) =================
    if (t > 0 && wid < 2) {
        int r = rb + wid;
        const float* pr = p32 + (long)r * H;
        float wmx = *wmax;
        float eps = 6.0e-5f * pnorm[r] * wmx + 3e-5f;

        float marr[4];
        float AM = -__builtin_inff();
        #pragma unroll
        for (int i = 0; i < 4; ++i) {
            int cc = lane + 64 * i;
            if (cc < NCHUNK) {
                float2 cv = cmsh[cc];
                marr[i] = wid ? cv.y : cv.x;
            } else marr[i] = -__builtin_inff();
            AM = fmaxf(AM, marr[i]);
        }
        #pragma unroll
        for (int off = 1; off < 64; off <<= 1) AM = fmaxf(AM, __shfl_xor(AM, off, 64));
        double S = 0.0;
        #pragma unroll
        for (int i = 0; i < 4; ++i) {
            int cc = lane + 64 * i;
            if (cc < NCHUNK) {
                float2 sv = cssh[cc];
                S += (double)(wid ? sv.y : sv.x);
            }
        }
        #pragma unroll
        for (int off = 1; off < 64; off <<= 1) S += __shfl_xor(S, off, 64);

        // pass A: exact max M over mask-selected elements; cache up to 2/lane
        float M = -__builtin_inff();
        float l0f = 0.f, l1f = 0.f;
        int v0i = 0, v1i = 0, nc = 0;
        bool spill = false;
        #pragma unroll 1
        for (int i = 0; i < 4; ++i) {
            unsigned long long mask = __ballot(marr[i] >= AM - eps);
            while (mask) {
                int bsl = __ffsll(mask) - 1;
                mask &= mask - 1;
                int cc = i * 64 + bsl;
                const unsigned long long* mk2 = maskbuf + ((long)cc * B + r) * 2;
                unsigned long long m0 = mk2[0], m1 = mk2[1];
                #pragma unroll 1
                for (int q = 0; q < 2; ++q) {
                    int cidx = q * 64 + lane;
                    if (mask_test(m0, m1, cidx)) {
                        int v = cc * 128 + cidx;
                        double acc = w2dot(pr, W2_raw, v, isf);
                        float l = __fadd_rn((float)acc, b2[v]);
                        M = fmaxf(M, l);
                        if (nc == 0)      { l0f = l; v0i = v; nc = 1; }
                        else if (nc == 1) { l1f = l; v1i = v; nc = 2; }
                        else spill = true;
                    }
                }
            }
        }
        #pragma unroll
        for (int off = 1; off < 64; off <<= 1) M = fmaxf(M, __shfl_xor(M, off, 64));

        float L = (float)(log(S) - (double)M);
        float negL = __fsub_rn(0.0f, L);

        // pass B: cached-register check (chunks partition v ascending, so
        // global min hit == old first-chunk min hit)
        int best = INT_MAX;
        if (__ballot(spill) == 0ull) {
            int hit = INT_MAX;
            if (nc >= 1) {
                float lp = __fsub_rn(__fsub_rn(l0f, M), L);
                if (lp == negL) hit = v0i;
            }
            if (nc >= 2) {
                float lp = __fsub_rn(__fsub_rn(l1f, M), L);
                if (lp == negL && v1i < hit) hit = v1i;
            }
            #pragma unroll
            for (int off = 1; off < 64; off <<= 1) {
                int oh = __shfl_xor(hit, off, 64);
                hit = (oh < hit) ? oh : hit;
            }
            best = hit;
        } else {
            #pragma unroll 1
            for (int i = 0; i < 4 && best == INT_MAX; ++i) {
                unsigned long long mask = __ballot(marr[i] >= AM - eps);
                while (mask && best == INT_MAX) {
                    int bsl = __ffsll(mask) - 1;
                    mask &= mask - 1;
                    int cc = i * 64 + bsl;
                    const unsigned long long* mk2 = maskbuf + ((long)cc * B + r) * 2;
                    unsigned long long m0 = mk2[0], m1 = mk2[1];
                    int hit = INT_MAX;
                    #pragma unroll 1
                    for (int q = 0; q < 2; ++q) {
                        int cidx = q * 64 + lane;
                        if (mask_test(m0, m1, cidx)) {
                            int v = cc * 128 + cidx;
                            double acc = w2dot(pr, W2_raw, v, isf);
                            float l  = __fadd_rn((float)acc, b2[v]);
                            float lp = __fsub_rn(__fsub_rn(l, M), L);
                            if (lp == negL && v < hit) hit = v;
                        }
                    }
                    #pragma unroll
                    for (int off = 1; off < 64; off <<= 1) {
                        int oh = __shfl_xor(hit, off, 64);
                        hit = (oh < hit) ? oh : hit;
                    }
                    if (hit != INT_MAX) best = hit;
                }
            }
        }
        int bi = (best == INT_MAX) ? 0 : best;

        int unfr = unf[r];
        float lp = negL;
        int itn = unfr ? bi : 0;
        int unfn = (unfr && itn != EOS) ? 1 : 0;
        if (lane == 0) { it[r] = itn; unf[r] = unfn; }
        if (lane < NS) {
            long ro = (long)r * NS + lane;
            int tm1 = t - 1;
            out[ro * T_STEPS + tm1] = (float)itn;
            out[(long)BFULL * T_STEPS + ro * T_STEPS + tm1] = lp;
            out[2L * BFULL * T_STEPS + ro * T_STEPS + tm1] = unfr ? 1.0f : 0.0f;
        }
    }
    __syncthreads();

    // ================= G: gates + cell + proj (rows rb, rb+1) =================
    {   // stage As: thread -> row (tid>>7), 2 consecutive elems
        int r = tid >> 7, kq = (tid & 127) * 2;
        long row = rb + r;
        int tok = it[row];
        float v0, v1;
        if (kq < H) {
            if (isf) {
                float2 f = *(const float2*)((const float*)embed_raw + (long)tok * H + kq);
                v0 = f.x; v1 = f.y;
            } else {
                ushort2 u = *(const ushort2*)((const unsigned short*)embed_raw + (long)tok * H + kq);
                v0 = bf2f(u.x); v1 = bf2f(u.y);
            }
        } else {
            float2 f = *(const float2*)(h + row * H + (kq - H));
            v0 = f.x; v1 = f.y;
        }
        As[r][kq] = v0; As[r][kq + 1] = v1;
    }
    __syncthreads();

    {   // gates: thread owns columns {tid, tid+256}; 2 rows; coalesced wT loads
        int c0 = tid, c1 = tid + 256;
        double acc[2][2] = {};
        const float2* wiA = (const float2*)wihT + c0;   // [kp][512] float2
        const float2* wiB = (const float2*)wihT + c1;
        #pragma unroll 8
        for (int kp = 0; kp < 64; ++kp) {
            float2 wa = wiA[kp * 512];
            float2 wb = wiB[kp * 512];
            #pragma unroll
            for (int r = 0; r < 2; ++r) {
                float2 a2 = *(const float2*)(&As[r][kp * 2]);
                double s0 = acc[r][0], s1 = acc[r][1];
                s0 += (double)a2.x * (double)wa.x;
                s0 += (double)a2.y * (double)wa.y;
                s1 += (double)a2.x * (double)wb.x;
                s1 += (double)a2.y * (double)wb.y;
                acc[r][0] = s0; acc[r][1] = s1;
            }
        }
        float t1[2][2];
        float bi0 = bih[c0], bi1 = bih[c1];
        #pragma unroll
        for (int r = 0; r < 2; ++r) {
            t1[r][0] = __fadd_rn((float)acc[r][0], bi0);
            t1[r][1] = __fadd_rn((float)acc[r][1], bi1);
            acc[r][0] = 0.0; acc[r][1] = 0.0;
        }
        const float2* whA = (const float2*)whhT + c0;
        const float2* whB = (const float2*)whhT + c1;
        #pragma unroll 8
        for (int kp = 0; kp < 64; ++kp) {
            float2 wa = whA[kp * 512];
            float2 wb = whB[kp * 512];
            #pragma unroll
            for (int r = 0; r < 2; ++r) {
                float2 a2 = *(const float2*)(&As[r][128 + kp * 2]);
                double s0 = acc[r][0], s1 = acc[r][1];
                s0 += (double)a2.x * (double)wa.x;
                s0 += (double)a2.y * (double)wa.y;
                s1 += (double)a2.x * (double)wb.x;
                s1 += (double)a2.y * (double)wb.y;
                acc[r][0] = s0; acc[r][1] = s1;
            }
        }
        float bh0 = bhh[c0], bh1 = bhh[c1];
        #pragma unroll
        for (int r = 0; r < 2; ++r) {
            gsh[r][c0] = __fadd_rn(__fadd_rn(t1[r][0], (float)acc[r][0]), bh0);
            gsh[r][c1] = __fadd_rn(__fadd_rn(t1[r][1], (float)acc[r][1]), bh1);
        }
    }
    __syncthreads();

    {   // cell: one element per thread (2 rows x 128)
        int lr = tid >> 7, j = tid & 127;
        long row = rb + lr;
        float gi = gsh[lr][j], gf = gsh[lr][j + 128], gg = gsh[lr][j + 256], go = gsh[lr][j + 384];
        float cv = c[row * 128 + j];
        float si = sig32(gi);
        float sf = sig32(gf);
        float so = sig32(go);
        float tg = tanh32(gg);
        float cn = __fadd_rn(__fmul_rn(sf, cv), __fmul_rn(si, tg));
        float hn = __fmul_rn(so, tanh32(cn));
        c[row * 128 + j] = cn;
        h[row * 128 + j] = hn;
        hl[lr][j] = hn;
    }
    __syncthreads();

    {   // proj + p-split + row ||p||: thread -> (row tid>>7, col tid&127)
        int j = tid & 127;
        int rr = tid >> 7;
        const float2* w12 = (const float2*)w1T + j;     // [kp][128] float2
        double acc = 0.0;
        #pragma unroll 8
        for (int kp = 0; kp < 64; ++kp) {
            float2 w = w12[kp * 128];
            float2 a2 = *(const float2*)(&hl[rr][kp * 2]);
            acc += (double)a2.x * (double)w.x;
            acc += (double)a2.y * (double)w.y;
        }
        long row = rb + rr;
        float pv = __fadd_rn((float)acc, b1[j]);
        p32[row * H + j] = pv;
        float ps = pv * 256.0f;
        f16 hh = (f16)ps;
        f16 ll = (f16)(ps - (float)hh);
        ((f16*)ph)[row * H + j] = hh;
        ((f16*)pl)[row * H + j] = ll;
        // row norm partial: waves 0-1 -> row 0, waves 2-3 -> row 1
        float sq = pv * pv;
        #pragma unroll
        for (int off = 1; off < 64; off <<= 1) sq += __shfl_xor(sq, off, 64);
        if (lane == 0) redp[wid] = sq;
    }
    __syncthreads();
    if (tid < 2) pnorm[rb + tid] = sqrtf(redp[2 * tid] + redp[2 * tid + 1]);
}

// ---------------------------------------------------------------- vocab scan via split-f16 MFMA + byte-packed element masks:
// 1024 blocks x 256 thr, 4 waves, 2 blocks/CU, XCD-grouped swizzle,
// transposed cm/cs [cb][row], gload_lds staging. (Stage-once geometries
// regress badly — r3/r13 — due to L2 thrash; keep the 4x-staged layout.)
// Mask emission ballot-free: each lane stores one byte (bit n = col n*16+tx).
__global__ __launch_bounds__(256, 2) void k_vscan_mfma(
    const unsigned short* __restrict__ ph_, const unsigned short* __restrict__ pl_,
    const unsigned short* __restrict__ whf_, const unsigned short* __restrict__ wlf_,
    const float* __restrict__ b2, const float* __restrict__ pnorm,
    const float* __restrict__ wmax,
    float* __restrict__ cmT, float* __restrict__ csT,
    unsigned long long* __restrict__ maskbuf) {
    __shared__ f16 Bsh[16384];   // 32 KB
    __shared__ f16 Bsl[16384];   // 32 KB
    const f16* ph  = (const f16*)ph_;
    const f16* pl  = (const f16*)pl_;
    int tid  = threadIdx.x;
    int lane = tid & 63, wid = tid >> 6;
    int tx = lane & 15, kg = lane >> 4;

    // bid = hi*32 + rb*8 + xcd  ->  cb = hi*8 + xcd
    int bid = blockIdx.x;
    int xcd = bid & 7, rb = (bid >> 3) & 3, hi = bid >> 5;
    int cb = hi * 8 + xcd;
    if (cb >= NCHUNK) return;
    int rbw = rb * 256 + wid * 64;
    int vb  = cb * 128;

    // stage B tile: linear 64KB direct-to-LDS
    {
        const f16* sh = (const f16*)whf_ + (long)cb * 16384;
        const f16* sl = (const f16*)wlf_ + (long)cb * 16384;
        #pragma unroll
        for (int i = 0; i < 8; ++i) {
            int g = tid + 256 * i;               // 16B chunk id, 0..2047
            __builtin_amdgcn_global_load_lds(
                (const AS1 void*)(const void*)(sh + (long)g * 8),
                (AS3 void*)(void*)(Bsh + g * 8), 16, 0, 0);
            __builtin_amdgcn_global_load_lds(
                (const AS1 void*)(const void*)(sl + (long)g * 8),
                (AS3 void*)(void*)(Bsl + g * 8), 16, 0, 0);
        }
    }
    __syncthreads();

    floatx4 acc[4][8];
    #pragma unroll
    for (int m = 0; m < 4; ++m)
        #pragma unroll
        for (int n = 0; n < 8; ++n)
            acc[m][n] = (floatx4){0.f, 0.f, 0.f, 0.f};

    int aoffs[4];
    #pragma unroll
    for (int m = 0; m < 4; ++m) aoffs[m] = (rbw + m * 16 + tx) * H + kg * 8;

    #pragma unroll
    for (int kk = 0; kk < 4; ++kk) {
        half8 Ah[4], Al[4];
        #pragma unroll
        for (int m = 0; m < 4; ++m) {
            Ah[m] = *(const half8*)(ph + aoffs[m] + kk * 32);
            Al[m] = *(const half8*)(pl + aoffs[m] + kk * 32);
        }
        int bbase = (kk * 4 + kg) * 1024 + tx * 8;
        #pragma unroll
        for (int n = 0; n < 8; ++n) {
            half8 Bh = *(const half8*)(Bsh + bbase + n * 128);
            half8 Bl = *(const half8*)(Bsl + bbase + n * 128);
            #pragma unroll
            for (int m = 0; m < 4; ++m)
                acc[m][n] = __builtin_amdgcn_mfma_f32_16x16x32_f16(Ah[m], Bh, acc[m][n], 0, 0, 0);
            #pragma unroll
            for (int m = 0; m < 4; ++m)
                acc[m][n] = __builtin_amdgcn_mfma_f32_16x16x32_f16(Ah[m], Bl, acc[m][n], 0, 0, 0);
            #pragma unroll
            for (int m = 0; m < 4; ++m)
                acc[m][n] = __builtin_amdgcn_mfma_f32_16x16x32_f16(Al[m], Bh, acc[m][n], 0, 0, 0);
        }
    }

    // epilogue: descale, bias, per-(row,chunk) max + expf-sum + byte mask.
    // C/D layout: col = n*16 + tx, row = kg*4 + reg (within m*16).
    const float S2 = 1.0f / 65536.0f;
    const float wmx = *wmax;
    float bb[8];
    #pragma unroll
    for (int n = 0; n < 8; ++n) bb[n] = b2[vb + n * 16 + tx];
    #pragma unroll
    for (int m = 0; m < 4; ++m) {
        #pragma unroll
        for (int r = 0; r < 4; ++r) {
            float l[8];
            float mxr = -__builtin_inff();
            float sr = 0.f;
            #pragma unroll
            for (int n = 0; n < 8; ++n) {
                l[n] = acc[m][n][r] * S2 + bb[n];
                mxr = fmaxf(mxr, l[n]);
                sr += __expf(l[n]);
            }
            #pragma unroll
            for (int off = 1; off < 16; off <<= 1) {
                mxr = fmaxf(mxr, __shfl_xor(mxr, off, 64));
                sr += __shfl_xor(sr, off, 64);
            }
            int row = rbw + m * 16 + kg * 4 + r;
            float thr = mxr - (6.0e-5f * pnorm[row] * wmx + 3.0e-5f);
            unsigned mb = 0;
            #pragma unroll
            for (int n = 0; n < 8; ++n)
                if (l[n] >= thr) mb |= (1u << n);
            ((unsigned char*)maskbuf)[((long)cb * B + row) * 16 + tx] = (unsigned char)mb;
            if (tx == 0) {
                cmT[(long)cb * B + row] = mxr;
                csT[(long)cb * B + row] = sr;
            }
        }
    }
}

// ---------------------------------------------------------------- tail finalize (t = T_STEPS-1), byte-mask-filtered
__global__ __launch_bounds__(256) void k_final(
    const float* __restrict__ cmT, const float* __restrict__ csT,
    const unsigned long long* __restrict__ maskbuf,
    const float* __restrict__ p32, const void* __restrict__ W2_raw,
    const float* __restrict__ b2, const float* __restrict__ wmax,
    const float* __restrict__ pnorm,
    int* __restrict__ it, int* __restrict__ unf,
    float* __restrict__ out, int t, const int* __restrict__ flag) {
    const bool isf = (*flag != 0);
    int r = blockIdx.x * 4 + (threadIdx.x >> 6);
    int lane = threadIdx.x & 63;
    const float* pr = p32 + (long)r * H;
    float wmx = *wmax;
    float eps = 6.0e-5f * pnorm[r] * wmx + 3e-5f;

    float marr[4];
    float AM = -__builtin_inff();
    #pragma unroll
    for (int i = 0; i < 4; ++i) {
        int cc = lane + 64 * i;
        marr[i] = (cc < NCHUNK) ? cmT[(long)cc * B + r] : -__builtin_inff();
        AM = fmaxf(AM, marr[i]);
    }
    #pragma unroll
    for (int off = 1; off < 64; off <<= 1) AM = fmaxf(AM, __shfl_xor(AM, off, 64));
    double S = 0.0;
    #pragma unroll
    for (int i = 0; i < 4; ++i) {
        int cc = lane + 64 * i;
        if (cc < NCHUNK) S += (double)csT[(long)cc * B + r];
    }
    #pragma unroll
    for (int off = 1; off < 64; off <<= 1) S += __shfl_xor(S, off, 64);

    float M = -__builtin_inff();
    #pragma unroll 1
    for (int i = 0; i < 4; ++i) {
        unsigned long long mask = __ballot(marr[i] >= AM - eps);
        while (mask) {
            int b = __ffsll(mask) - 1;
            mask &= mask - 1;
            int cc = i * 64 + b;
            const unsigned long long* mk2 = maskbuf + ((long)cc * B + r) * 2;
            unsigned long long m0 = mk2[0], m1 = mk2[1];
            #pragma unroll 1
            for (int q = 0; q < 2; ++q) {
                int cidx = q * 64 + lane;
                if (mask_test(m0, m1, cidx)) {
                    int v = cc * 128 + cidx;
                    double acc = w2dot(pr, W2_raw, v, isf);
                    float l = __fadd_rn((float)acc, b2[v]);
                    M = fmaxf(M, l);
                }
            }
        }
    }
    #pragma unroll
    for (int off = 1; off < 64; off <<= 1) M = fmaxf(M, __shfl_xor(M, off, 64));

    float L = (float)(log(S) - (double)M);
    float negL = __fsub_rn(0.0f, L);

    int best = INT_MAX;
    #pragma unroll 1
    for (int i = 0; i < 4 && best == INT_MAX; ++i) {
        unsigned long long mask = __ballot(marr[i] >= AM - eps);
        while (mask && best == INT_MAX) {
            int b = __ffsll(mask) - 1;
            mask &= mask - 1;
            int cc = i * 64 + b;
            const unsigned long long* mk2 = maskbuf + ((long)cc * B + r) * 2;
            unsigned long long m0 = mk2[0], m1 = mk2[1];
            int hit = INT_MAX;
            #pragma unroll 1
            for (int q = 0; q < 2; ++q) {
                int cidx = q * 64 + lane;
                if (mask_test(m0, m1, cidx)) {
                    int v = cc * 128 + cidx;
                    double acc = w2dot(pr, W2_raw, v, isf);
                    float l  = __fadd_rn((float)acc, b2[v]);
                    float lp = __fsub_rn(__fsub_rn(l, M), L);
                    if (lp == negL && v < hit) hit = v;
                }
            }
            #pragma unroll
            for (int off = 1; off < 64; off <<= 1) {
                int oh = __shfl_xor(hit, off, 64);
                hit = (oh < hit) ? oh : hit;
            }
            if (hit != INT_MAX) best = hit;
        }
    }
    int bi = (best == INT_MAX) ? 0 : best;

    int unfr = unf[r];
    float lp = negL;
    int itn = unfr ? bi : 0;
    int unfn = (unfr && itn != EOS) ? 1 : 0;
    if (lane == 0) { it[r] = itn; unf[r] = unfn; }
    if (lane < NS) {
        long ro = (long)r * NS + lane;
        out[ro * T_STEPS + t] = (float)itn;
        out[(long)BFULL * T_STEPS + ro * T_STEPS + t] = lp;
        out[2L * BFULL * T_STEPS + ro * T_STEPS + t] = unfr ? 1.0f : 0.0f;
    }
}

// ---------------------------------------------------------------- launch
extern "C" void kernel_launch(void* const* d_in, const int* in_sizes, int n_in,
                              void* d_out, int out_size, void* d_ws, size_t ws_size,
                              hipStream_t stream) {
    float* out = (float*)d_out;

    char* w = (char*)d_ws;
    float* fin[12];
    for (int i = 0; i < 12; ++i) {
        if (i == 1 || i == 10) { fin[i] = nullptr; continue; }   // embed/W2 read raw
        fin[i] = (float*)w;
        size_t bytes = ((size_t)in_sizes[i] * 4 + 15) & ~(size_t)15;
        w += bytes;
    }
    float*  h     = (float*) w; w += (size_t)B * H * 4;
    float*  c     = (float*) w; w += (size_t)B * H * 4;
    float*  p32   = (float*) w; w += (size_t)B * H * 4;
    float*  cm    = (float*) w; w += (size_t)B * NCHUNK * 4;
    float*  cs    = (float*) w; w += (size_t)B * NCHUNK * 4;
    float*  wn    = (float*) w; w += (size_t)V * 4;
    float*  wmax  = (float*) w; w += 16;
    float*  pnorm = (float*) w; w += (size_t)B * 4;
    int*    it    = (int*)   w; w += (size_t)B * 4;
    int*    unf   = (int*)   w; w += (size_t)B * 4;
    int*    flag  = (int*)   w; w += 16;
    float*  wihT  = (float*) w; w += (size_t)512 * 128 * 4;
    float*  whhT  = (float*) w; w += (size_t)512 * 128 * 4;
    float*  w1T   = (float*) w; w += (size_t)128 * 128 * 4;
    unsigned long long* maskbuf = (unsigned long long*)w; w += (size_t)NCHUNK * B * 16;
    unsigned short* ph = (unsigned short*)w; w += (size_t)B * H * 2;
    unsigned short* pl = (unsigned short*)w; w += (size_t)B * H * 2;
    unsigned short* wh = (unsigned short*)w; w += (size_t)V * H * 2;
    unsigned short* wl = (unsigned short*)w; w += (size_t)V * H * 2;

    k_detect<<<1, 64, 0, stream>>>((const unsigned short*)d_in[1], flag);

    // one dispatch for all transcodes
    TCArgs tc;
    int maxn = 0;
    for (int i = 0; i < 12; ++i) {
        tc.src[i] = d_in[i];
        tc.dst[i] = fin[i];
        tc.n[i]   = in_sizes[i];
        if (fin[i] && in_sizes[i] > maxn) maxn = in_sizes[i];
    }
    k_transcode_all<<<dim3((maxn + 255) / 256, 12), 256, 0, stream>>>(tc, flag);

    k_wsplit<<<(V * H / 8 + 255) / 256, 256, 0, stream>>>(d_in[10], wh, wl, wn, flag);
    k_wtr<<<(2 * 512 * 128 + 128 * 128 + 255) / 256, 256, 0, stream>>>(
        fin[4], fin[6], fin[8], wihT, whhT, w1T);
    k_prep<<<5, 256, 0, stream>>>(wn, wmax, it, unf);

    const float* xf  = fin[0];
    const float* Wfc = fin[2];
    const float* bfc = fin[3];
    const float* bih = fin[5];
    const float* bhh = fin[7];
    const float* b1  = fin[9];
    const float* b2  = fin[11];

    k_init_hc<<<B, 256, 0, stream>>>(xf, Wfc, bfc, h, c);

    for (int t = 0; t < T_STEPS; ++t) {
        k_gf<<<B / 2, 256, 0, stream>>>(cm, cs, maskbuf, d_in[10], b2, wmax,
                                        d_in[1], h, c, wihT, whhT, bih, bhh,
                                        w1T, b1, p32, ph, pl, pnorm, it, unf, out, t, flag);
        k_vscan_mfma<<<1024, 256, 0, stream>>>(ph, pl, wh, wl, b2, pnorm, wmax, cm, cs, maskbuf);
    }
    k_final<<<B / 4, 256, 0, stream>>>(cm, cs, maskbuf, p32, d_in[10], b2, wmax, pnorm,
                                       it, unf, out, T_STEPS - 1, flag);
}

// Round 16
// 1523.215 us; speedup vs baseline: 1.4334x; 1.4334x over previous
//
#include <hip/hip_runtime.h>
#include <math.h>
#include <limits.h>

#define H 128
#define V 32000
#define CD 256
#define T_STEPS 21
#define NS 5
#define SOS 1
#define EOS 2
#define B 1024          // unique rows; reference B=5120 is 5 identical copies of each
#define BFULL 5120
#define NCHUNK 250      // V / 128

typedef _Float16 f16;
typedef f16   half8   __attribute__((ext_vector_type(8)));
typedef float floatx4 __attribute__((ext_vector_type(4)));
typedef unsigned short ushort8v __attribute__((ext_vector_type(8)));

#define AS1 __attribute__((address_space(1)))
#define AS3 __attribute__((address_space(3)))

__device__ __forceinline__ float bf2f(unsigned short u) {
    return __uint_as_float(((unsigned)u) << 16);
}

// np-faithful f32 sigmoid/tanh: f64 interior, single f32 round per np op.
__device__ __forceinline__ float sig32(float x) {
    float t = (float)exp(-(double)x);
    float r = __fadd_rn(1.0f, t);
    return __fdiv_rn(1.0f, r);
}
__device__ __forceinline__ float tanh32(float x) { return (float)tanh((double)x); }

// exact f64-recipe dot of p-row (f32, global) with W2 row v, k ascending.
// Vectorized loads; f64 add order identical to the scalar loop -> bit-identical.
__device__ __forceinline__ double w2dot(const float* __restrict__ pr,
                                        const void* __restrict__ W2_raw,
                                        int v, bool isf) {
    double acc = 0.0;
    if (isf) {
        const float* wv = (const float*)W2_raw + (long)v * H;
        #pragma unroll 8
        for (int k4 = 0; k4 < H / 4; ++k4) {
            float4 wq = *(const float4*)(wv + k4 * 4);
            float4 pq = *(const float4*)(pr + k4 * 4);
            acc += (double)pq.x * (double)wq.x;
            acc += (double)pq.y * (double)wq.y;
            acc += (double)pq.z * (double)wq.z;
            acc += (double)pq.w * (double)wq.w;
        }
    } else {
        const unsigned short* wv = (const unsigned short*)W2_raw + (long)v * H;
        #pragma unroll 8
        for (int k4 = 0; k4 < H / 4; ++k4) {
            ushort4 u = *(const ushort4*)(wv + k4 * 4);
            float4 pq = *(const float4*)(pr + k4 * 4);
            acc += (double)pq.x * (double)bf2f(u.x);
            acc += (double)pq.y * (double)bf2f(u.y);
            acc += (double)pq.z * (double)bf2f(u.z);
            acc += (double)pq.w * (double)bf2f(u.w);
        }
    }
    return acc;
}

// mask bit index for col c (0..127) in the byte-packed 128-bit record:
// byte (c&15) holds bits n for cols n*16+(c&15); bit index = (c&15)*8 + (c>>4).
__device__ __forceinline__ bool mask_test(unsigned long long m0, unsigned long long m1, int c) {
    int bidx = ((c & 15) << 3) + (c >> 4);
    unsigned long long word = (bidx < 64) ? m0 : m1;
    return (word >> (bidx & 63)) & 1ull;
}

// ---------------------------------------------------------------- input dtype sniffer
__global__ void k_detect(const unsigned short* __restrict__ e, int* __restrict__ flag) {
    int i = threadIdx.x;
    unsigned short u = e[2 * i];
    int ex = (u >> 7) & 0xFF;
    bool wild = ((u & 0x7FFF) != 0) && (ex < 0x60 || ex > 0x8F);
    unsigned long long m = __ballot(wild);
    if (i == 0) *flag = (m != 0ull) ? 1 : 0;   // 1 = f32 inputs, 0 = bf16
}

// ---------------------------------------------------------------- transcode ALL f32-bound inputs in one dispatch
struct TCArgs {
    const void* src[12];
    float*      dst[12];
    int         n[12];
};
__global__ __launch_bounds__(256) void k_transcode_all(TCArgs tc, const int* __restrict__ flag) {
    int which = blockIdx.y;
    float* d = tc.dst[which];
    if (d == nullptr) return;
    int i = blockIdx.x * 256 + threadIdx.x;
    if (i >= tc.n[which]) return;
    if (*flag) d[i] = ((const float*)tc.src[which])[i];
    else       d[i] = bf2f(((const unsigned short*)tc.src[which])[i]);
}

// ---------------------------------------------------------------- transpose Wih/Whh/W1 to k-pair-major [kp][col][2]
__global__ __launch_bounds__(256) void k_wtr(
    const float* __restrict__ Wih, const float* __restrict__ Whh,
    const float* __restrict__ W1, float* __restrict__ wihT,
    float* __restrict__ whhT, float* __restrict__ w1T) {
    int e = blockIdx.x * 256 + threadIdx.x;
    if (e < 512 * 128) {
        int col = e >> 7, k = e & 127;
        wihT[(k >> 1) * 1024 + col * 2 + (k & 1)] = Wih[e];
    } else if (e < 2 * 512 * 128) {
        int i = e - 512 * 128;
        int col = i >> 7, k = i & 127;
        whhT[(k >> 1) * 1024 + col * 2 + (k & 1)] = Whh[i];
    } else if (e < 2 * 512 * 128 + 128 * 128) {
        int i = e - 2 * 512 * 128;
        int col = i >> 7, k = i & 127;
        w1T[(k >> 1) * 256 + col * 2 + (k & 1)] = W1[i];
    }
}

// ---------------------------------------------------------------- W2: coalesced norm + scaled f16 hi/lo split (once per launch)
// Fragment-major wh/wl: f16 index = cb*16384 + kkg*1024 + row_local*8 + j.
__global__ __launch_bounds__(256) void k_wsplit(
    const void* __restrict__ W2_raw, unsigned short* __restrict__ wh,
    unsigned short* __restrict__ wl, float* __restrict__ wn,
    const int* __restrict__ flag) {
    int t = blockIdx.x * 256 + threadIdx.x;       // t in [0, V*H/8)
    const bool isf = (*flag != 0);
    int vrow = t >> 4;                            // vocab row
    int kkg  = t & 15;                            // which 8-wide k group
    float v[8];
    if (isf) {
        float4 f0 = ((const float4*)W2_raw)[2 * t];
        float4 f1 = ((const float4*)W2_raw)[2 * t + 1];
        v[0] = f0.x; v[1] = f0.y; v[2] = f0.z; v[3] = f0.w;
        v[4] = f1.x; v[5] = f1.y; v[6] = f1.z; v[7] = f1.w;
    } else {
        ushort8v u = ((const ushort8v*)W2_raw)[t];
        #pragma unroll
        for (int i = 0; i < 8; ++i) v[i] = bf2f(u[i]);
    }
    float s = 0.f;
    half8 hv, lv;
    #pragma unroll
    for (int i = 0; i < 8; ++i) {
        s += v[i] * v[i];
        float ws = v[i] * 256.0f;
        f16 hh = (f16)ws;
        hv[i] = hh;
        lv[i] = (f16)(ws - (float)hh);
    }
    int cb = vrow >> 7, rloc = vrow & 127;
    long dst = (long)cb * 16384 + kkg * 1024 + rloc * 8;
    *(half8*)((f16*)wh + dst) = hv;
    *(half8*)((f16*)wl + dst) = lv;
    // row norm: 16 consecutive threads share a row
    #pragma unroll
    for (int off = 1; off < 16; off <<= 1) s += __shfl_xor(s, off, 64);
    if (kkg == 0) wn[vrow] = sqrtf(s);
}

// ---------------------------------------------------------------- prep: wmax (block 4) + it/unf init (blocks 0-3)
__global__ __launch_bounds__(256) void k_prep(
    const float* __restrict__ wn, float* __restrict__ wmax,
    int* __restrict__ it, int* __restrict__ unf) {
    int tid = threadIdx.x;
    if (blockIdx.x < 4) {
        int i = blockIdx.x * 256 + tid;
        it[i] = SOS; unf[i] = 1;
        return;
    }
    __shared__ float red[4];
    float m = 0.f;
    for (int i = tid; i < V; i += 256) m = fmaxf(m, wn[i]);
    #pragma unroll
    for (int off = 1; off < 64; off <<= 1) m = fmaxf(m, __shfl_xor(m, off, 64));
    if ((tid & 63) == 0) red[tid >> 6] = m;
    __syncthreads();
    if (tid == 0) *wmax = fmaxf(fmaxf(red[0], red[1]), fmaxf(red[2], red[3]));
}

// ---------------------------------------------------------------- hc = fl32(x @ W_fc.T) + b_fc
__global__ __launch_bounds__(256) void k_init_hc(
    const float* __restrict__ xf, const float* __restrict__ Wfc,
    const float* __restrict__ bfc, float* __restrict__ h, float* __restrict__ c) {
    __shared__ float xl[CD];
    int r = blockIdx.x;
    int j = threadIdx.x;
    xl[j] = xf[(long)r * CD + j];
    __syncthreads();
    const float4* w4 = (const float4*)(Wfc + (long)j * CD);
    double acc = 0.0;
    for (int k4 = 0; k4 < CD / 4; ++k4) {
        float4 w = w4[k4];
        int k = k4 * 4;
        acc += (double)xl[k]     * (double)w.x;
        acc += (double)xl[k + 1] * (double)w.y;
        acc += (double)xl[k + 2] * (double)w.z;
        acc += (double)xl[k + 3] * (double)w.w;
    }
    float hc = __fadd_rn((float)acc, bfc[j]);
    if (j < H) h[(long)r * H + j] = hc;
    else       c[(long)r * H + (j - H)] = hc;
}

// ---------------------------------------------------------------- fused F(t-1) + G(t), 512 blocks x 512 threads, 2 rows/block
// (2 blocks/CU = 16 waves/CU). Phase F (waves 0-1): mask-selected exact
// rescue, block-staged cm/cs, register-cached pass B (spill fallback).
// Phase G: transposed-weight gates/cell/proj. All f64 chains bit-identical.
// NOTE r15: shrinking to 256 thr + launch_bounds(256,4) capped VGPR at 64
// -> f64 accumulator spill, 2.2x slower. Keep 512 thr / 116 VGPR.
__global__ __launch_bounds__(512) void k_gf(
    const float* __restrict__ cmT, const float* __restrict__ csT,
    const unsigned long long* __restrict__ maskbuf,
    const void* __restrict__ W2_raw,
    const float* __restrict__ b2, const float* __restrict__ wmax,
    const void* __restrict__ embed_raw, float* __restrict__ h, float* __restrict__ c,
    const float* __restrict__ wihT, const float* __restrict__ whhT,
    const float* __restrict__ bih, const float* __restrict__ bhh,
    const float* __restrict__ w1T, const float* __restrict__ b1,
    float* __restrict__ p32, unsigned short* __restrict__ ph,
    unsigned short* __restrict__ pl, float* __restrict__ pnorm,
    int* __restrict__ it, int* __restrict__ unf, float* __restrict__ out,
    int t, const int* __restrict__ flag) {
    __shared__ float As[2][256];    // concat(e_tok, h) per row
    __shared__ float gsh[2][512];   // gates
    __shared__ float hl[2][132];
    __shared__ float2 cmsh[256];    // staged cm for rows rb, rb+1
    __shared__ float2 cssh[256];
    __shared__ float redp[4];
    const bool isf = (*flag != 0);
    int tid = threadIdx.x;
    int rb = blockIdx.x * 2;
    int lane = tid & 63, wid = tid >> 6;

    // ---- stage cm/cs for this block's 2 rows (parallel scattered loads)
    if (t > 0 && tid < NCHUNK) {
        cmsh[tid] = *(const float2*)(cmT + (long)tid * B + rb);
        cssh[tid] = *(const float2*)(csT + (long)tid * B + rb);
    }
    __syncthreads();

    // ================= F: finalize step t-1 for row rb+wid (waves 0-1) =================
    if (t > 0 && wid < 2) {
        int r = rb + wid;
        const float* pr = p32 + (long)r * H;
        float wmx = *wmax;
        float eps = 6.0e-5f * pnorm[r] * wmx + 3e-5f;

        float marr[4];
        float AM = -__builtin_inff();
        #pragma unroll
        for (int i = 0; i < 4; ++i) {
            int cc = lane + 64 * i;
            if (cc < NCHUNK) {
                float2 cv = cmsh[cc];
                marr[i] = wid ? cv.y : cv.x;
            } else marr[i] = -__builtin_inff();
            AM = fmaxf(AM, marr[i]);
        }
        #pragma unroll
        for (int off = 1; off < 64; off <<= 1) AM = fmaxf(AM, __shfl_xor(AM, off, 64));
        double S = 0.0;
        #pragma unroll
        for (int i = 0; i < 4; ++i) {
            int cc = lane + 64 * i;
            if (cc < NCHUNK) {
                float2 sv = cssh[cc];
                S += (double)(wid ? sv.y : sv.x);
            }
        }
        #pragma unroll
        for (int off = 1; off < 64; off <<= 1) S += __shfl_xor(S, off, 64);

        // pass A: exact max M over mask-selected elements; cache up to 2/lane
        float M = -__builtin_inff();
        float l0f = 0.f, l1f = 0.f;
        int v0i = 0, v1i = 0, nc = 0;
        bool spill = false;
        #pragma unroll 1
        for (int i = 0; i < 4; ++i) {
            unsigned long long mask = __ballot(marr[i] >= AM - eps);
            while (mask) {
                int bsl = __ffsll(mask) - 1;
                mask &= mask - 1;
                int cc = i * 64 + bsl;
                const unsigned long long* mk2 = maskbuf + ((long)cc * B + r) * 2;
                unsigned long long m0 = mk2[0], m1 = mk2[1];
                #pragma unroll 1
                for (int q = 0; q < 2; ++q) {
                    int cidx = q * 64 + lane;
                    if (mask_test(m0, m1, cidx)) {
                        int v = cc * 128 + cidx;
                        double acc = w2dot(pr, W2_raw, v, isf);
                        float l = __fadd_rn((float)acc, b2[v]);
                        M = fmaxf(M, l);
                        if (nc == 0)      { l0f = l; v0i = v; nc = 1; }
                        else if (nc == 1) { l1f = l; v1i = v; nc = 2; }
                        else spill = true;
                    }
                }
            }
        }
        #pragma unroll
        for (int off = 1; off < 64; off <<= 1) M = fmaxf(M, __shfl_xor(M, off, 64));

        float L = (float)(log(S) - (double)M);
        float negL = __fsub_rn(0.0f, L);

        // pass B: cached-register check (chunks partition v ascending, so
        // global min hit == old first-chunk min hit)
        int best = INT_MAX;
        if (__ballot(spill) == 0ull) {
            int hit = INT_MAX;
            if (nc >= 1) {
                float lp = __fsub_rn(__fsub_rn(l0f, M), L);
                if (lp == negL) hit = v0i;
            }
            if (nc >= 2) {
                float lp = __fsub_rn(__fsub_rn(l1f, M), L);
                if (lp == negL && v1i < hit) hit = v1i;
            }
            #pragma unroll
            for (int off = 1; off < 64; off <<= 1) {
                int oh = __shfl_xor(hit, off, 64);
                hit = (oh < hit) ? oh : hit;
            }
            best = hit;
        } else {
            #pragma unroll 1
            for (int i = 0; i < 4 && best == INT_MAX; ++i) {
                unsigned long long mask = __ballot(marr[i] >= AM - eps);
                while (mask && best == INT_MAX) {
                    int bsl = __ffsll(mask) - 1;
                    mask &= mask - 1;
                    int cc = i * 64 + bsl;
                    const unsigned long long* mk2 = maskbuf + ((long)cc * B + r) * 2;
                    unsigned long long m0 = mk2[0], m1 = mk2[1];
                    int hit = INT_MAX;
                    #pragma unroll 1
                    for (int q = 0; q < 2; ++q) {
                        int cidx = q * 64 + lane;
                        if (mask_test(m0, m1, cidx)) {
                            int v = cc * 128 + cidx;
                            double acc = w2dot(pr, W2_raw, v, isf);
                            float l  = __fadd_rn((float)acc, b2[v]);
                            float lp = __fsub_rn(__fsub_rn(l, M), L);
                            if (lp == negL && v < hit) hit = v;
                        }
                    }
                    #pragma unroll
                    for (int off = 1; off < 64; off <<= 1) {
                        int oh = __shfl_xor(hit, off, 64);
                        hit = (oh < hit) ? oh : hit;
                    }
                    if (hit != INT_MAX) best = hit;
                }
            }
        }
        int bi = (best == INT_MAX) ? 0 : best;

        int unfr = unf[r];
        float lp = negL;
        int itn = unfr ? bi : 0;
        int unfn = (unfr && itn != EOS) ? 1 : 0;
        if (lane == 0) { it[r] = itn; unf[r] = unfn; }
        if (lane < NS) {
            long ro = (long)r * NS + lane;
            int tm1 = t - 1;
            out[ro * T_STEPS + tm1] = (float)itn;
            out[(long)BFULL * T_STEPS + ro * T_STEPS + tm1] = lp;
            out[2L * BFULL * T_STEPS + ro * T_STEPS + tm1] = unfr ? 1.0f : 0.0f;
        }
    }
    __syncthreads();

    // ================= G: gates + cell + proj (rows rb, rb+1) =================
    {   // stage As: thread -> row (tid>>8), 1 elem
        int r = tid >> 8, kq = tid & 255;
        long row = rb + r;
        int tok = it[row];
        float v0;
        if (kq < H) {
            if (isf) v0 = ((const float*)embed_raw)[(long)tok * H + kq];
            else     v0 = bf2f(((const unsigned short*)embed_raw)[(long)tok * H + kq]);
        } else {
            v0 = h[row * H + (kq - H)];
        }
        As[r][kq] = v0;
    }
    __syncthreads();

    {   // gates: thread owns ONE gate column cg = tid; 2 rows; coalesced wT loads
        int cg = tid;
        double acc[2] = {};
        const float2* wi2 = (const float2*)wihT + cg;   // [kp][512] float2
        #pragma unroll 8
        for (int kp = 0; kp < 64; ++kp) {
            float2 w = wi2[kp * 512];
            #pragma unroll
            for (int r = 0; r < 2; ++r) {
                float2 a2 = *(const float2*)(&As[r][kp * 2]);
                double s0 = acc[r];
                s0 += (double)a2.x * (double)w.x;
                s0 += (double)a2.y * (double)w.y;
                acc[r] = s0;
            }
        }
        float t1[2];
        float bi = bih[cg];
        #pragma unroll
        for (int r = 0; r < 2; ++r) {
            t1[r] = __fadd_rn((float)acc[r], bi);
            acc[r] = 0.0;
        }
        const float2* wh2 = (const float2*)whhT + cg;
        #pragma unroll 8
        for (int kp = 0; kp < 64; ++kp) {
            float2 w = wh2[kp * 512];
            #pragma unroll
            for (int r = 0; r < 2; ++r) {
                float2 a2 = *(const float2*)(&As[r][128 + kp * 2]);
                double s0 = acc[r];
                s0 += (double)a2.x * (double)w.x;
                s0 += (double)a2.y * (double)w.y;
                acc[r] = s0;
            }
        }
        float bh = bhh[cg];
        #pragma unroll
        for (int r = 0; r < 2; ++r)
            gsh[r][cg] = __fadd_rn(__fadd_rn(t1[r], (float)acc[r]), bh);
    }
    __syncthreads();

    if (tid < 256) {   // cell: one element per thread (2 rows x 128)
        int lr = tid >> 7, j = tid & 127;
        long row = rb + lr;
        float gi = gsh[lr][j], gf = gsh[lr][j + 128], gg = gsh[lr][j + 256], go = gsh[lr][j + 384];
        float cv = c[row * 128 + j];
        float si = sig32(gi);
        float sf = sig32(gf);
        float so = sig32(go);
        float tg = tanh32(gg);
        float cn = __fadd_rn(__fmul_rn(sf, cv), __fmul_rn(si, tg));
        float hn = __fmul_rn(so, tanh32(cn));
        c[row * 128 + j] = cn;
        h[row * 128 + j] = hn;
        hl[lr][j] = hn;
    }
    __syncthreads();

    if (tid < 256) {   // proj + p-split + row ||p||: thread -> (row tid>>7, col tid&127)
        int j = tid & 127;
        int rr = tid >> 7;
        const float2* w12 = (const float2*)w1T + j;     // [kp][128] float2
        double acc = 0.0;
        #pragma unroll 8
        for (int kp = 0; kp < 64; ++kp) {
            float2 w = w12[kp * 128];
            float2 a2 = *(const float2*)(&hl[rr][kp * 2]);
            acc += (double)a2.x * (double)w.x;
            acc += (double)a2.y * (double)w.y;
        }
        long row = rb + rr;
        float pv = __fadd_rn((float)acc, b1[j]);
        p32[row * H + j] = pv;
        float ps = pv * 256.0f;
        f16 hh = (f16)ps;
        f16 ll = (f16)(ps - (float)hh);
        ((f16*)ph)[row * H + j] = hh;
        ((f16*)pl)[row * H + j] = ll;
        // row norm partial: reduce pv^2 within each of waves 0-3
        float sq = pv * pv;
        #pragma unroll
        for (int off = 1; off < 64; off <<= 1) sq += __shfl_xor(sq, off, 64);
        if (lane == 0) redp[wid] = sq;
    }
    __syncthreads();
    if (tid < 2) pnorm[rb + tid] = sqrtf(redp[2 * tid] + redp[2 * tid + 1]);
}

// ---------------------------------------------------------------- vocab scan via split-f16 MFMA + byte-packed element masks:
// 1024 blocks x 256 thr, 4 waves, 2 blocks/CU, XCD-grouped swizzle,
// transposed cm/cs [cb][row], gload_lds staging. (Stage-once geometries
// regress badly — r3/r13 — due to L2 thrash; keep the 4x-staged layout.)
// Mask emission ballot-free: each lane stores one byte (bit n = col n*16+tx).
__global__ __launch_bounds__(256, 2) void k_vscan_mfma(
    const unsigned short* __restrict__ ph_, const unsigned short* __restrict__ pl_,
    const unsigned short* __restrict__ whf_, const unsigned short* __restrict__ wlf_,
    const float* __restrict__ b2, const float* __restrict__ pnorm,
    const float* __restrict__ wmax,
    float* __restrict__ cmT, float* __restrict__ csT,
    unsigned long long* __restrict__ maskbuf) {
    __shared__ f16 Bsh[16384];   // 32 KB
    __shared__ f16 Bsl[16384];   // 32 KB
    const f16* ph  = (const f16*)ph_;
    const f16* pl  = (const f16*)pl_;
    int tid  = threadIdx.x;
    int lane = tid & 63, wid = tid >> 6;
    int tx = lane & 15, kg = lane >> 4;

    // bid = hi*32 + rb*8 + xcd  ->  cb = hi*8 + xcd
    int bid = blockIdx.x;
    int xcd = bid & 7, rb = (bid >> 3) & 3, hi = bid >> 5;
    int cb = hi * 8 + xcd;
    if (cb >= NCHUNK) return;
    int rbw = rb * 256 + wid * 64;
    int vb  = cb * 128;

    // stage B tile: linear 64KB direct-to-LDS
    {
        const f16* sh = (const f16*)whf_ + (long)cb * 16384;
        const f16* sl = (const f16*)wlf_ + (long)cb * 16384;
        #pragma unroll
        for (int i = 0; i < 8; ++i) {
            int g = tid + 256 * i;               // 16B chunk id, 0..2047
            __builtin_amdgcn_global_load_lds(
                (const AS1 void*)(const void*)(sh + (long)g * 8),
                (AS3 void*)(void*)(Bsh + g * 8), 16, 0, 0);
            __builtin_amdgcn_global_load_lds(
                (const AS1 void*)(const void*)(sl + (long)g * 8),
                (AS3 void*)(void*)(Bsl + g * 8), 16, 0, 0);
        }
    }
    __syncthreads();

    floatx4 acc[4][8];
    #pragma unroll
    for (int m = 0; m < 4; ++m)
        #pragma unroll
        for (int n = 0; n < 8; ++n)
            acc[m][n] = (floatx4){0.f, 0.f, 0.f, 0.f};

    int aoffs[4];
    #pragma unroll
    for (int m = 0; m < 4; ++m) aoffs[m] = (rbw + m * 16 + tx) * H + kg * 8;

    #pragma unroll
    for (int kk = 0; kk < 4; ++kk) {
        half8 Ah[4], Al[4];
        #pragma unroll
        for (int m = 0; m < 4; ++m) {
            Ah[m] = *(const half8*)(ph + aoffs[m] + kk * 32);
            Al[m] = *(const half8*)(pl + aoffs[m] + kk * 32);
        }
        int bbase = (kk * 4 + kg) * 1024 + tx * 8;
        #pragma unroll
        for (int n = 0; n < 8; ++n) {
            half8 Bh = *(const half8*)(Bsh + bbase + n * 128);
            half8 Bl = *(const half8*)(Bsl + bbase + n * 128);
            #pragma unroll
            for (int m = 0; m < 4; ++m)
                acc[m][n] = __builtin_amdgcn_mfma_f32_16x16x32_f16(Ah[m], Bh, acc[m][n], 0, 0, 0);
            #pragma unroll
            for (int m = 0; m < 4; ++m)
                acc[m][n] = __builtin_amdgcn_mfma_f32_16x16x32_f16(Ah[m], Bl, acc[m][n], 0, 0, 0);
            #pragma unroll
            for (int m = 0; m < 4; ++m)
                acc[m][n] = __builtin_amdgcn_mfma_f32_16x16x32_f16(Al[m], Bh, acc[m][n], 0, 0, 0);
        }
    }

    // epilogue: descale, bias, per-(row,chunk) max + expf-sum + byte mask.
    // C/D layout: col = n*16 + tx, row = kg*4 + reg (within m*16).
    const float S2 = 1.0f / 65536.0f;
    const float wmx = *wmax;
    float bb[8];
    #pragma unroll
    for (int n = 0; n < 8; ++n) bb[n] = b2[vb + n * 16 + tx];
    #pragma unroll
    for (int m = 0; m < 4; ++m) {
        #pragma unroll
        for (int r = 0; r < 4; ++r) {
            float l[8];
            float mxr = -__builtin_inff();
            float sr = 0.f;
            #pragma unroll
            for (int n = 0; n < 8; ++n) {
                l[n] = acc[m][n][r] * S2 + bb[n];
                mxr = fmaxf(mxr, l[n]);
                sr += __expf(l[n]);
            }
            #pragma unroll
            for (int off = 1; off < 16; off <<= 1) {
                mxr = fmaxf(mxr, __shfl_xor(mxr, off, 64));
                sr += __shfl_xor(sr, off, 64);
            }
            int row = rbw + m * 16 + kg * 4 + r;
            float thr = mxr - (6.0e-5f * pnorm[row] * wmx + 3.0e-5f);
            unsigned mb = 0;
            #pragma unroll
            for (int n = 0; n < 8; ++n)
                if (l[n] >= thr) mb |= (1u << n);
            ((unsigned char*)maskbuf)[((long)cb * B + row) * 16 + tx] = (unsigned char)mb;
            if (tx == 0) {
                cmT[(long)cb * B + row] = mxr;
                csT[(long)cb * B + row] = sr;
            }
        }
    }
}

// ---------------------------------------------------------------- tail finalize (t = T_STEPS-1), byte-mask-filtered
__global__ __launch_bounds__(256) void k_final(
    const float* __restrict__ cmT, const float* __restrict__ csT,
    const unsigned long long* __restrict__ maskbuf,
    const float* __restrict__ p32, const void* __restrict__ W2_raw,
    const float* __restrict__ b2, const float* __restrict__ wmax,
    const float* __restrict__ pnorm,
    int* __restrict__ it, int* __restrict__ unf,
    float* __restrict__ out, int t, const int* __restrict__ flag) {
    const bool isf = (*flag != 0);
    int r = blockIdx.x * 4 + (threadIdx.x >> 6);
    int lane = threadIdx.x & 63;
    const float* pr = p32 + (long)r * H;
    float wmx = *wmax;
    float eps = 6.0e-5f * pnorm[r] * wmx + 3e-5f;

    float marr[4];
    float AM = -__builtin_inff();
    #pragma unroll
    for (int i = 0; i < 4; ++i) {
        int cc = lane + 64 * i;
        marr[i] = (cc < NCHUNK) ? cmT[(long)cc * B + r] : -__builtin_inff();
        AM = fmaxf(AM, marr[i]);
    }
    #pragma unroll
    for (int off = 1; off < 64; off <<= 1) AM = fmaxf(AM, __shfl_xor(AM, off, 64));
    double S = 0.0;
    #pragma unroll
    for (int i = 0; i < 4; ++i) {
        int cc = lane + 64 * i;
        if (cc < NCHUNK) S += (double)csT[(long)cc * B + r];
    }
    #pragma unroll
    for (int off = 1; off < 64; off <<= 1) S += __shfl_xor(S, off, 64);

    float M = -__builtin_inff();
    #pragma unroll 1
    for (int i = 0; i < 4; ++i) {
        unsigned long long mask = __ballot(marr[i] >= AM - eps);
        while (mask) {
            int b = __ffsll(mask) - 1;
            mask &= mask - 1;
            int cc = i * 64 + b;
            const unsigned long long* mk2 = maskbuf + ((long)cc * B + r) * 2;
            unsigned long long m0 = mk2[0], m1 = mk2[1];
            #pragma unroll 1
            for (int q = 0; q < 2; ++q) {
                int cidx = q * 64 + lane;
                if (mask_test(m0, m1, cidx)) {
                    int v = cc * 128 + cidx;
                    double acc = w2dot(pr, W2_raw, v, isf);
                    float l = __fadd_rn((float)acc, b2[v]);
                    M = fmaxf(M, l);
                }
            }
        }
    }
    #pragma unroll
    for (int off = 1; off < 64; off <<= 1) M = fmaxf(M, __shfl_xor(M, off, 64));

    float L = (float)(log(S) - (double)M);
    float negL = __fsub_rn(0.0f, L);

    int best = INT_MAX;
    #pragma unroll 1
    for (int i = 0; i < 4 && best == INT_MAX; ++i) {
        unsigned long long mask = __ballot(marr[i] >= AM - eps);
        while (mask && best == INT_MAX) {
            int b = __ffsll(mask) - 1;
            mask &= mask - 1;
            int cc = i * 64 + b;
            const unsigned long long* mk2 = maskbuf + ((long)cc * B + r) * 2;
            unsigned long long m0 = mk2[0], m1 = mk2[1];
            int hit = INT_MAX;
            #pragma unroll 1
            for (int q = 0; q < 2; ++q) {
                int cidx = q * 64 + lane;
                if (mask_test(m0, m1, cidx)) {
                    int v = cc * 128 + cidx;
                    double acc = w2dot(pr, W2_raw, v, isf);
                    float l  = __fadd_rn((float)acc, b2[v]);
                    float lp = __fsub_rn(__fsub_rn(l, M), L);
                    if (lp == negL && v < hit) hit = v;
                }
            }
            #pragma unroll
            for (int off = 1; off < 64; off <<= 1) {
                int oh = __shfl_xor(hit, off, 64);
                hit = (oh < hit) ? oh : hit;
            }
            if (hit != INT_MAX) best = hit;
        }
    }
    int bi = (best == INT_MAX) ? 0 : best;

    int unfr = unf[r];
    float lp = negL;
    int itn = unfr ? bi : 0;
    int unfn = (unfr && itn != EOS) ? 1 : 0;
    if (lane == 0) { it[r] = itn; unf[r] = unfn; }
    if (lane < NS) {
        long ro = (long)r * NS + lane;
        out[ro * T_STEPS + t] = (float)itn;
        out[(long)BFULL * T_STEPS + ro * T_STEPS + t] = lp;
        out[2L * BFULL * T_STEPS + ro * T_STEPS + t] = unfr ? 1.0f : 0.0f;
    }
}

// ---------------------------------------------------------------- launch
extern "C" void kernel_launch(void* const* d_in, const int* in_sizes, int n_in,
                              void* d_out, int out_size, void* d_ws, size_t ws_size,
                              hipStream_t stream) {
    float* out = (float*)d_out;

    char* w = (char*)d_ws;
    float* fin[12];
    for (int i = 0; i < 12; ++i) {
        if (i == 1 || i == 10) { fin[i] = nullptr; continue; }   // embed/W2 read raw
        fin[i] = (float*)w;
        size_t bytes = ((size_t)in_sizes[i] * 4 + 15) & ~(size_t)15;
        w += bytes;
    }
    float*  h     = (float*) w; w += (size_t)B * H * 4;
    float*  c     = (float*) w; w += (size_t)B * H * 4;
    float*  p32   = (float*) w; w += (size_t)B * H * 4;
    float*  cm    = (float*) w; w += (size_t)B * NCHUNK * 4;
    float*  cs    = (float*) w; w += (size_t)B * NCHUNK * 4;
    float*  wn    = (float*) w; w += (size_t)V * 4;
    float*  wmax  = (float*) w; w += 16;
    float*  pnorm = (float*) w; w += (size_t)B * 4;
    int*    it    = (int*)   w; w += (size_t)B * 4;
    int*    unf   = (int*)   w; w += (size_t)B * 4;
    int*    flag  = (int*)   w; w += 16;
    float*  wihT  = (float*) w; w += (size_t)512 * 128 * 4;
    float*  whhT  = (float*) w; w += (size_t)512 * 128 * 4;
    float*  w1T   = (float*) w; w += (size_t)128 * 128 * 4;
    unsigned long long* maskbuf = (unsigned long long*)w; w += (size_t)NCHUNK * B * 16;
    unsigned short* ph = (unsigned short*)w; w += (size_t)B * H * 2;
    unsigned short* pl = (unsigned short*)w; w += (size_t)B * H * 2;
    unsigned short* wh = (unsigned short*)w; w += (size_t)V * H * 2;
    unsigned short* wl = (unsigned short*)w; w += (size_t)V * H * 2;

    k_detect<<<1, 64, 0, stream>>>((const unsigned short*)d_in[1], flag);

    // one dispatch for all transcodes
    TCArgs tc;
    int maxn = 0;
    for (int i = 0; i < 12; ++i) {
        tc.src[i] = d_in[i];
        tc.dst[i] = fin[i];
        tc.n[i]   = in_sizes[i];
        if (fin[i] && in_sizes[i] > maxn) maxn = in_sizes[i];
    }
    k_transcode_all<<<dim3((maxn + 255) / 256, 12), 256, 0, stream>>>(tc, flag);

    k_wsplit<<<(V * H / 8 + 255) / 256, 256, 0, stream>>>(d_in[10], wh, wl, wn, flag);
    k_wtr<<<(2 * 512 * 128 + 128 * 128 + 255) / 256, 256, 0, stream>>>(
        fin[4], fin[6], fin[8], wihT, whhT, w1T);
    k_prep<<<5, 256, 0, stream>>>(wn, wmax, it, unf);

    const float* xf  = fin[0];
    const float* Wfc = fin[2];
    const float* bfc = fin[3];
    const float* bih = fin[5];
    const float* bhh = fin[7];
    const float* b1  = fin[9];
    const float* b2  = fin[11];

    k_init_hc<<<B, 256, 0, stream>>>(xf, Wfc, bfc, h, c);

    for (int t = 0; t < T_STEPS; ++t) {
        k_gf<<<B / 2, 512, 0, stream>>>(cm, cs, maskbuf, d_in[10], b2, wmax,
                                        d_in[1], h, c, wihT, whhT, bih, bhh,
                                        w1T, b1, p32, ph, pl, pnorm, it, unf, out, t, flag);
        k_vscan_mfma<<<1024, 256, 0, stream>>>(ph, pl, wh, wl, b2, pnorm, wmax, cm, cs, maskbuf);
    }
    k_final<<<B / 4, 256, 0, stream>>>(cm, cs, maskbuf, p32, d_in[10], b2, wmax, pnorm,
                                       it, unf, out, T_STEPS - 1, flag);
}